// Round 10
// baseline (587.238 us; speedup 1.0000x reference)
//
#include <hip/hip_runtime.h>
#include <math.h>

#define Bb 8
#define Nn 2048
#define Mm 2048
#define Cc 512

typedef __attribute__((ext_vector_type(8))) _Float16 hfrag;  // 8 f16 = 4 VGPRs
typedef __attribute__((ext_vector_type(4))) float f4;        // MFMA acc
typedef __attribute__((ext_vector_type(4))) _Float16 h4;

__device__ __forceinline__ void gld16(const void* g, void* l) {
    __builtin_amdgcn_global_load_lds(
        (const __attribute__((address_space(1))) void*)g,
        (__attribute__((address_space(3))) void*)l, 16, 0, 0);
}

// counted vmcnt wait + scheduler fence (rule #18) -- used by gemm_mfma
template<int N> __device__ __forceinline__ void wait_vmcnt() {
    if constexpr (N == 0)      asm volatile("s_waitcnt vmcnt(0)" ::: "memory");
    else if constexpr (N == 3) asm volatile("s_waitcnt vmcnt(3)" ::: "memory");
    else if constexpr (N == 4) asm volatile("s_waitcnt vmcnt(4)" ::: "memory");
    __builtin_amdgcn_sched_barrier(0);
}

// ---------------------------------------------------------------------------
// Fragment-blocked layouts (proven r9: 335->242us vs row-major scatter).
//   EB enc [8][m/16][c/32][16][32]: e(m,c) at (m>>4)*8192+(c>>5)*512+(m&15)*32+(c&31)
//   DB dec [8][n/16][c/32][16][32]: same with n
//   VB v   [8][c/16][m/32][16][32]: (c>>4)*32768+(m>>5)*512+(c&15)*32+(m&31)
// A wave's MFMA fragment load (lane addr = lcol*32 + quad*8) is ONE
// contiguous 1KB transaction.
// ---------------------------------------------------------------------------

// fp32 -> f16: linear copy (optional) + fragment-blocked copy.
__global__ __launch_bounds__(256) void sconv2(const float* __restrict__ x,
                                              _Float16* __restrict__ lin,
                                              _Float16* __restrict__ blk)
{
    const size_t i = (size_t)blockIdx.x * 256 + threadIdx.x;
    f4 v = ((const f4*)x)[i];
    h4 hh;
    #pragma unroll
    for (int k = 0; k < 4; ++k) hh[k] = (_Float16)v[k];
    if (lin) ((h4*)lin)[i] = hh;
    const size_t e0 = i * 4;
    const size_t b = e0 >> 20;                 // 2048*512 = 1M elems/batch
    const int    w = (int)(e0 & 1048575);
    const int    r = w >> 9, c = w & 511;      // c multiple of 4
    *(h4*)(blk + b * 1048576 +
           ((r >> 4) * 8192 + (c >> 5) * 512 + (r & 15) * 32 + (c & 31))) = hh;
}

// ---------------------------------------------------------------------------
// attn_fused v4 = v3 + register-budget fix + explicit pipelines.
// r9 post-mortem: VGPR_Count=128 (compiler targeted 4 waves/EU; grid caps
// us at 2) -> ~24MB scratch spill + no in-flight load depth; all pipes
// <12% = latency-serialized. Fixes:
//   (1) amdgpu_waves_per_eu(2,2): regalloc for exactly 2 waves/EU -> 256
//       VGPR budget, no spill. Free: grid (512=2 blk/CU) caps occupancy.
//   (2) S/PV phases: explicit 2-deep register pipelines (load frags t+1
//       during MFMA t; static unrolled indices).
//   (3) mask loads hoisted to S-phase start (900cy HBM latency hides
//       under 16 MFMA steps).
// Semantics byte-identical to r9 (passed, absmax 0.0078125).
// ---------------------------------------------------------------------------
__global__ __launch_bounds__(256)
__attribute__((amdgpu_waves_per_eu(2, 2)))
void attn_fused(
    const _Float16* __restrict__ EBg,  // enc blocked
    const _Float16* __restrict__ DBg,  // dec blocked
    const _Float16* __restrict__ VBg,  // v blocked
    const float*    __restrict__ Mg,   // mask [8][2048][2048] fp32
    _Float16* __restrict__ Gg)         // g out [8][2048][512] linear
{
    __shared__ _Float16 PL[32 * 256];      // P tile, 16 KB, XOR-swizzled
    __shared__ float MXS[4][32];
    __shared__ float LSS[4][32];

    const int id = blockIdx.x;
    const int bz = id & 7;                 // batch -> XCD
    const int n0 = (id >> 3) * 32;

    const _Float16* E0 = EBg + (size_t)bz * ((size_t)Mm * Cc);
    const _Float16* D0 = DBg + (size_t)bz * ((size_t)Nn * Cc);
    const _Float16* V0 = VBg + (size_t)bz * ((size_t)Cc * Mm);
    const float*    M0 = Mg  + (size_t)bz * ((size_t)Nn * Mm);

    const int tid = threadIdx.x;
    const int wv = tid >> 6, ln = tid & 63;
    const int lcol = ln & 15, quad = ln >> 4;
    const int eoff = lcol * 32 + quad * 8;     // lane offset within 1KB frag
    char* PLb = (char*)PL;

    // fragment base pointers
    const _Float16* Qf = D0 + (n0 >> 4) * 8192 + eoff;       // + j*8192 + t*512
    const _Float16* Ef = E0 + (wv * 4) * 8192 + eoff;        // + ((m0>>4)+i)*8192 + t*512
    const _Float16* Vf = V0 + (wv * 8) * 32768 + eoff;       // + i*32768 + ((m0>>5)+t)*512

    f4 o[8][2];                            // c = wv*128+i*16+quad*4+r, n = j*16+lcol
    const f4 z4 = {0.f, 0.f, 0.f, 0.f};
    #pragma unroll
    for (int i = 0; i < 8; ++i)
        #pragma unroll
        for (int j = 0; j < 2; ++j) o[i][j] = z4;
    float mrun[2] = {0.f, 0.f};            // init 0 = masked zeros participate
    float lrun[2] = {0.f, 0.f};

    for (int mt = 0; mt < 8; ++mt) {
        const int m0 = mt * 256;

        // ---- mask prefetch (HBM, hides under the whole S-phase) --------
        const float* Mkb = M0 + (size_t)(n0 + lcol) * Mm + m0 + wv * 64 + quad * 4;
        f4 mk[2][4];
        #pragma unroll
        for (int j = 0; j < 2; ++j)
            #pragma unroll
            for (int i = 0; i < 4; ++i)
                mk[j][i] = *(const f4*)(Mkb + (size_t)j * 16 * Mm + i * 16);

        // ---- S-phase: sa += enc x Q, 2-deep register pipeline ----------
        f4 sa[4][2];
        #pragma unroll
        for (int i = 0; i < 4; ++i)
            #pragma unroll
            for (int j = 0; j < 2; ++j) sa[i][j] = z4;

        hfrag afP[4], bfP[2], afN[4], bfN[2];
        #pragma unroll
        for (int i = 0; i < 4; ++i)
            afP[i] = *(const hfrag*)(Ef + (size_t)((m0 >> 4) + i) * 8192);
        #pragma unroll
        for (int j = 0; j < 2; ++j)
            bfP[j] = *(const hfrag*)(Qf + (size_t)j * 8192);

        #pragma unroll
        for (int t = 0; t < 16; ++t) {
            if (t + 1 < 16) {
                #pragma unroll
                for (int i = 0; i < 4; ++i)
                    afN[i] = *(const hfrag*)(Ef + (size_t)((m0 >> 4) + i) * 8192 + (t + 1) * 512);
                #pragma unroll
                for (int j = 0; j < 2; ++j)
                    bfN[j] = *(const hfrag*)(Qf + (size_t)j * 8192 + (t + 1) * 512);
            }
            #pragma unroll
            for (int i = 0; i < 4; ++i)
                #pragma unroll
                for (int j = 0; j < 2; ++j)
                    sa[i][j] = __builtin_amdgcn_mfma_f32_16x16x32_f16(afP[i], bfP[j], sa[i][j], 0, 0, 0);
            if (t + 1 < 16) {
                #pragma unroll
                for (int i = 0; i < 4; ++i) afP[i] = afN[i];
                #pragma unroll
                for (int j = 0; j < 2; ++j) bfP[j] = bfN[j];
            }
        }

        // ---- A-phase: mask + wave-local max ----------------------------
        #pragma unroll
        for (int j = 0; j < 2; ++j) {
            #pragma unroll
            for (int i = 0; i < 4; ++i)
                #pragma unroll
                for (int r = 0; r < 4; ++r) sa[i][j][r] *= mk[j][i][r];
            float mx = 0.f;
            #pragma unroll
            for (int i = 0; i < 4; ++i)
                #pragma unroll
                for (int r = 0; r < 4; ++r) mx = fmaxf(mx, sa[i][j][r]);
            mx = fmaxf(mx, __shfl_xor(mx, 16, 64));
            mx = fmaxf(mx, __shfl_xor(mx, 32, 64));
            if (quad == 0) MXS[wv][j * 16 + lcol] = mx;
        }
        __syncthreads();                                   // S1

        // ---- B-phase: m_new/alpha, P -> PL, l-partials -----------------
        float al[2], mnew[2];
        #pragma unroll
        for (int j = 0; j < 2; ++j) {
            const int n = j * 16 + lcol;
            float mm = mrun[j];
            mm = fmaxf(mm, MXS[0][n]); mm = fmaxf(mm, MXS[1][n]);
            mm = fmaxf(mm, MXS[2][n]); mm = fmaxf(mm, MXS[3][n]);
            al[j] = __expf(mrun[j] - mm);
            mrun[j] = mm; mnew[j] = mm;
        }
        #pragma unroll
        for (int j = 0; j < 2; ++j) {
            const int n = j * 16 + lcol;
            float lp = 0.f;
            #pragma unroll
            for (int i = 0; i < 4; ++i) {
                h4 pv;
                #pragma unroll
                for (int r = 0; r < 4; ++r) {
                    const float s = sa[i][j][r];
                    const float e = __expf(s - mnew[j]);
                    lp += e;
                    pv[r] = (s == 0.f) ? (_Float16)0.f : (_Float16)e;
                }
                *(h4*)(PLb + n * 512 +
                       (((wv << 7) + (i << 5) + (quad << 3)) ^ ((n & 7) << 4))) = pv;
            }
            lp += __shfl_xor(lp, 16, 64);
            lp += __shfl_xor(lp, 32, 64);
            if (quad == 0) LSS[wv][n] = lp;
        }
        __syncthreads();                                   // S2

        // ---- C-phase: l_run update + o rescale -------------------------
        #pragma unroll
        for (int j = 0; j < 2; ++j) {
            const int n = j * 16 + lcol;
            const float ls = LSS[0][n] + LSS[1][n] + LSS[2][n] + LSS[3][n];
            lrun[j] = lrun[j] * al[j] + ls;
            #pragma unroll
            for (int i = 0; i < 8; ++i)
                #pragma unroll
                for (int r = 0; r < 4; ++r) o[i][j][r] *= al[j];
        }

        // ---- PV-phase: o += v x P, 2-deep register pipeline ------------
        {
            hfrag vaP[8], vaN[8];
            #pragma unroll
            for (int i = 0; i < 8; ++i)
                vaP[i] = *(const hfrag*)(Vf + (size_t)i * 32768 + (size_t)(m0 >> 5) * 512);
            #pragma unroll
            for (int t = 0; t < 8; ++t) {
                if (t + 1 < 8) {
                    #pragma unroll
                    for (int i = 0; i < 8; ++i)
                        vaN[i] = *(const hfrag*)(Vf + (size_t)i * 32768 +
                                                 (size_t)((m0 >> 5) + t + 1) * 512);
                }
                hfrag pb[2];
                #pragma unroll
                for (int j = 0; j < 2; ++j) {
                    const int n = j * 16 + lcol;
                    pb[j] = *(const hfrag*)(PLb + n * 512 +
                            (((t << 6) + (quad << 4)) ^ ((n & 7) << 4)));
                }
                #pragma unroll
                for (int i = 0; i < 8; ++i)
                    #pragma unroll
                    for (int j = 0; j < 2; ++j)
                        o[i][j] = __builtin_amdgcn_mfma_f32_16x16x32_f16(vaP[i], pb[j], o[i][j], 0, 0, 0);
                if (t + 1 < 8) {
                    #pragma unroll
                    for (int i = 0; i < 8; ++i) vaP[i] = vaN[i];
                }
            }
        }
        __syncthreads();                                   // S3: PL reusable
    }

    // ---- finalize: g = dec * (1 + tanh(o/l)), dec read from DB blocked --
    _Float16* Gb = Gg + (size_t)bz * ((size_t)Nn * Cc);
    #pragma unroll
    for (int j = 0; j < 2; ++j) {
        const int n = n0 + j * 16 + lcol;
        const float inv = 1.f / lrun[j];
        const _Float16* Dn = D0 + (size_t)(n >> 4) * 8192 + (n & 15) * 32;
        #pragma unroll
        for (int i = 0; i < 8; ++i) {
            const int c0 = wv * 128 + i * 16 + quad * 4;
            const h4 dv = *(const h4*)(Dn + (c0 >> 5) * 512 + (c0 & 31));
            h4 gv;
            #pragma unroll
            for (int r = 0; r < 4; ++r) {
                const float a = o[i][j][r] * inv;
                const float th = 1.f - 2.f / (__expf(2.f * a) + 1.f);
                gv[r] = (_Float16)((float)dv[r] * (1.f + th));
            }
            *(h4*)(Gb + (size_t)n * Cc + c0) = gv;
        }
    }
}

// ---------------------------------------------------------------------------
// MFMA GEMM (f16 in, fp32 acc), 128xBN tile, BK=32, ring-of-3 LDS buffers,
// counted vmcnt + raw s_barrier (r3 structure, verified). EPI 1/3/4.
// EPI1 writes v into BLOCKED layout VB[b][c/16][m/32][16][32].
// ---------------------------------------------------------------------------
template<int EPI, int BN, int SWZ>
__global__ __launch_bounds__(256) void gemm_mfma(
    const _Float16* __restrict__ Ah, long sA, int lda,
    const _Float16* __restrict__ Bh, long sB, int ldb,
    const float* __restrict__ aux, long sAux, int ldaux,     // f32 bias
    void* __restrict__ Cout, long sC, int ldc, int K, int GX)
{
    constexpr int NI  = (BN == 128) ? 4 : 2;
    constexpr int ASL = 512;
    constexpr int BSL = BN * 4;
    constexpr int NQ  = (ASL + BSL) / 256;

    __shared__ _Float16 As[3][128 * 32];
    __shared__ _Float16 Bs[3][BN * 32];

    int bx, by, bz;
    if (SWZ == 1) {
        const int id = blockIdx.x;
        bz = id & 7; bx = (id >> 3) % GX; by = (id >> 3) / GX;
    } else if (SWZ == 2) {
        const int id = blockIdx.x;
        bz = 0; bx = (id >> 3) % GX; by = (id & 7) + 8 * ((id >> 3) / GX);
    } else {
        bx = blockIdx.x; by = blockIdx.y; bz = 0;
    }

    const _Float16* A0 = Ah + (size_t)bz * sA;
    const _Float16* B0 = Bh + (size_t)bz * sB;

    const int tid  = threadIdx.x;
    const int wv   = tid >> 6;
    const int ln   = tid & 63;
    const int wx   = (BN == 128) ? (wv & 1) : 0;
    const int wy   = (BN == 128) ? (wv >> 1) : wv;
    const int lcol = ln & 15, quad = ln >> 4;
    const int row0w = wy * (NI * 16);
    const int col0w = wx * 64;

    const int rowBase = by * 128;
    const int colBase = bx * BN;
    const int soff = (quad ^ ((lcol >> 1) & 3)) * 8;

    f4 acc[NI][4];
    const f4 z4 = {0.f, 0.f, 0.f, 0.f};
    #pragma unroll
    for (int i = 0; i < NI; ++i)
        #pragma unroll
        for (int j = 0; j < 4; ++j) acc[i][j] = z4;

    auto STAGE = [&](int k0, int p) {
        #pragma unroll
        for (int q = 0; q < NQ; ++q) {
            const int c = q * 256 + wv * 64 + ln;
            if (c < ASL) {
                const int r = c >> 2;
                const int g = (c & 3) ^ ((c >> 3) & 3);
                gld16(A0 + (size_t)(rowBase + r) * lda + k0 + g * 8, &As[p][c * 8]);
            } else {
                const int cb = c - ASL;
                const int r  = cb >> 2;
                const int g  = (cb & 3) ^ ((cb >> 3) & 3);
                gld16(B0 + (size_t)(colBase + r) * ldb + k0 + g * 8, &Bs[p][cb * 8]);
            }
        }
    };

    const int NT = K >> 5;
    STAGE(0, 0);
    STAGE(32, 1);
    wait_vmcnt<NQ>();
    __builtin_amdgcn_s_barrier();

    int p = 0, pn2 = 2;
    for (int t = 0; t < NT; ++t) {
        if (t + 2 < NT) STAGE((t + 2) * 32, pn2);

        hfrag af[NI], bf_[4];
        #pragma unroll
        for (int i = 0; i < NI; ++i)
            af[i]  = *(const hfrag*)&As[p][(row0w + i * 16 + lcol) * 32 + soff];
        #pragma unroll
        for (int j = 0; j < 4; ++j)
            bf_[j] = *(const hfrag*)&Bs[p][(col0w + j * 16 + lcol) * 32 + soff];

        #pragma unroll
        for (int i = 0; i < NI; ++i)
            #pragma unroll
            for (int j = 0; j < 4; ++j)
                acc[i][j] = __builtin_amdgcn_mfma_f32_16x16x32_f16(af[i], bf_[j], acc[i][j], 0, 0, 0);

        if (t + 1 < NT) {
            if (t + 2 < NT) wait_vmcnt<NQ>();
            else            wait_vmcnt<0>();
            __builtin_amdgcn_s_barrier();
        }
        p   = (p   == 2) ? 0 : p + 1;
        pn2 = (pn2 == 2) ? 0 : pn2 + 1;
    }

    const int crow0 = rowBase + row0w + quad * 4;
    const int ccol0 = colBase + col0w + lcol;

    if (EPI == 1) {            // v blocked: VB[b][c/16][m/32][16][32]
        _Float16* C = (_Float16*)Cout;
        #pragma unroll
        for (int j = 0; j < 4; ++j) {
            const int col = ccol0 + j * 16;          // c index
            const float bi = aux[col];
            #pragma unroll
            for (int i = 0; i < NI; ++i) {
                const int rowb = crow0 + i * 16;     // flattened b*M + m
                const int bb = rowb >> 11, ml = rowb & 2047;
                h4 st;
                #pragma unroll
                for (int r = 0; r < 4; ++r) st[r] = (_Float16)(acc[i][j][r] + bi);
                *(h4*)(C + (size_t)bb * 1048576 +
                       ((col >> 4) * 32768 + (ml >> 5) * 512 +
                        (col & 15) * 32 + (ml & 31))) = st;
            }
        }
    } else if (EPI == 3) {     // fc1: h[n][c2] = relu(acc + b1[c2]), h4
        _Float16* C = (_Float16*)Cout;
        #pragma unroll
        for (int i = 0; i < NI; ++i) {
            const int c0 = crow0 + i * 16;
            const f4 bi = *(const f4*)(aux + c0);
            #pragma unroll
            for (int j = 0; j < 4; ++j) {
                const int n = ccol0 + j * 16;
                h4 hv;
                #pragma unroll
                for (int r = 0; r < 4; ++r)
                    hv[r] = (_Float16)fmaxf(acc[i][j][r] + bi[r], 0.f);
                *(h4*)(C + (size_t)n * ldc + c0) = hv;
            }
        }
    } else {                   // fc2: out[n][c3] = acc + b2[c3], f4 stores
        float* C = (float*)Cout;
        #pragma unroll
        for (int i = 0; i < NI; ++i) {
            const int c0 = crow0 + i * 16;
            const f4 bi = *(const f4*)(aux + c0);
            #pragma unroll
            for (int j = 0; j < 4; ++j) {
                const int n = ccol0 + j * 16;
                f4 ov;
                #pragma unroll
                for (int r = 0; r < 4; ++r) ov[r] = acc[i][j][r] + bi[r];
                *(f4*)(C + (size_t)n * ldc + c0) = ov;
            }
        }
    }
}

// W [512,512] fp32 -> Wt [512,512] f16 transposed (Wt[n][k] = W[k][n]).
__global__ __launch_bounds__(256) void wconv(const float* s0, const float* s1, const float* s2,
                                             _Float16* d0, _Float16* d1, _Float16* d2)
{
    const float* Sm = blockIdx.z == 0 ? s0 : blockIdx.z == 1 ? s1 : s2;
    _Float16* D = blockIdx.z == 0 ? d0 : blockIdx.z == 1 ? d1 : d2;
    __shared__ float t[32][33];
    const int x = threadIdx.x & 31, y = threadIdx.x >> 5;
    const int gx = blockIdx.x * 32, gy = blockIdx.y * 32;
    #pragma unroll
    for (int yy = y; yy < 32; yy += 8)
        t[yy][x] = Sm[(size_t)(gy + yy) * 512 + gx + x];
    __syncthreads();
    #pragma unroll
    for (int yy = y; yy < 32; yy += 8)
        D[(size_t)(gx + yy) * 512 + gy + x] = (_Float16)t[x][yy];
}

// ---------------------------------------------------------------------------
// ws layout (all within proven 142MB envelope):
//   EB   [0x0000000, 0x1000000)  enc blocked f16
//   DB   [0x1000000, 0x2000000)  dec blocked f16
//   VB   [0x2000000, 0x3000000)  v blocked f16
//   Wvt/W1t/W2t [0x5600000, +3*512KB)
//   g    [0x6800000, 0x7800000)  f16 [bn][c]
//   h    [0x7800000, 0x8800000)  f16 [bn][c2]
//   enc_h linear in d_out (dead before fc2 writes).
// ---------------------------------------------------------------------------
extern "C" void kernel_launch(void* const* d_in, const int* in_sizes, int n_in,
                              void* d_out, int out_size, void* d_ws, size_t ws_size,
                              hipStream_t stream)
{
    const float* dec   = (const float*)d_in[0];
    const float* enc   = (const float*)d_in[1];
    const float* trans = (const float*)d_in[2];
    const float* Wv = (const float*)d_in[3];
    const float* bv = (const float*)d_in[4];
    const float* W1 = (const float*)d_in[5];
    const float* b1 = (const float*)d_in[6];
    const float* W2 = (const float*)d_in[7];
    const float* b2 = (const float*)d_in[8];

    char* ws = (char*)d_ws;
    _Float16* EBw   = (_Float16*)ws;
    _Float16* DBw   = (_Float16*)(ws + 0x1000000);
    _Float16* VBw   = (_Float16*)(ws + 0x2000000);
    _Float16* Wvt   = (_Float16*)(ws + 0x5600000);
    _Float16* W1t   = Wvt + 262144;
    _Float16* W2t   = Wvt + 524288;
    _Float16* g     = (_Float16*)(ws + 0x6800000);
    _Float16* h     = (_Float16*)(ws + 0x7800000);
    _Float16* enc_h = (_Float16*)d_out;

    sconv2<<<dim3(8192), 256, 0, stream>>>(dec, nullptr, DBw);
    sconv2<<<dim3(8192), 256, 0, stream>>>(enc, enc_h, EBw);
    wconv<<<dim3(16, 16, 3), 256, 0, stream>>>(Wv, W1, W2, Wvt, W1t, W2t);

    // v = (enc @ Wv + bv), written fragment-blocked  [SWZ2, GX=8]
    gemm_mfma<1, 64, 2><<<dim3(1024), 256, 0, stream>>>(
        enc_h, 0, 512, Wvt, 0, 512, bv, 0, 0,
        VBw, 0, 0, 512, 8);

    // fused: score + masked-softmax + PV + gate -> g  (blocked operands)
    attn_fused<<<dim3(512), 256, 0, stream>>>(EBw, DBw, VBw, trans, g);

    // h[n][c2] = relu(g @ W1 + b1):  A=W1^T (rows=c2), B=g (cols=n)
    gemm_mfma<3, 64, 0><<<dim3(256, 4), 256, 0, stream>>>(
        W1t, 0, 512, g, 0, 512, b1, 0, 0,
        h, 0, 512, 512, 0);

    // out[n][c3] = h @ W2 + b2:  A=W2^T (rows=c3), B=h (cols=n), fp32
    gemm_mfma<4, 64, 0><<<dim3(256, 4), 256, 0, stream>>>(
        W2t, 0, 512, h, 0, 512, b2, 0, 0,
        d_out, 0, 512, 512, 0);
}

// Round 11
// 475.460 us; speedup vs baseline: 1.2351x; 1.2351x over previous
//
#include <hip/hip_runtime.h>
#include <math.h>

#define Bb 8
#define Nn 2048
#define Mm 2048
#define Cc 512

typedef __attribute__((ext_vector_type(8))) _Float16 hfrag;  // 8 f16 = 4 VGPRs
typedef __attribute__((ext_vector_type(4))) float f4;        // MFMA acc
typedef __attribute__((ext_vector_type(4))) _Float16 h4;

__device__ __forceinline__ void gld16(const void* g, void* l) {
    __builtin_amdgcn_global_load_lds(
        (const __attribute__((address_space(1))) void*)g,
        (__attribute__((address_space(3))) void*)l, 16, 0, 0);
}

// counted vmcnt wait + scheduler fence (rule #18) -- used by gemm_mfma
template<int N> __device__ __forceinline__ void wait_vmcnt() {
    if constexpr (N == 0)      asm volatile("s_waitcnt vmcnt(0)" ::: "memory");
    else if constexpr (N == 3) asm volatile("s_waitcnt vmcnt(3)" ::: "memory");
    else if constexpr (N == 4) asm volatile("s_waitcnt vmcnt(4)" ::: "memory");
    __builtin_amdgcn_sched_barrier(0);
}

// ---------------------------------------------------------------------------
// Fragment-blocked layouts (proven r9: 335->242us vs row-major scatter).
//   EB enc [8][m/16][c/32][16][32]: e(m,c) at (m>>4)*8192+(c>>5)*512+(m&15)*32+(c&31)
//   DB dec [8][n/16][c/32][16][32]: same with n
//   VB v   [8][c/16][m/32][16][32]: (c>>4)*32768+(m>>5)*512+(c&15)*32+(m&31)
// A wave's MFMA fragment load (lane addr = lcol*32 + quad*8) is ONE
// contiguous 1KB transaction.
// ---------------------------------------------------------------------------

// fp32 -> f16: linear copy (optional) + fragment-blocked copy.
__global__ __launch_bounds__(256) void sconv2(const float* __restrict__ x,
                                              _Float16* __restrict__ lin,
                                              _Float16* __restrict__ blk)
{
    const size_t i = (size_t)blockIdx.x * 256 + threadIdx.x;
    f4 v = ((const f4*)x)[i];
    h4 hh;
    #pragma unroll
    for (int k = 0; k < 4; ++k) hh[k] = (_Float16)v[k];
    if (lin) ((h4*)lin)[i] = hh;
    const size_t e0 = i * 4;
    const size_t b = e0 >> 20;                 // 2048*512 = 1M elems/batch
    const int    w = (int)(e0 & 1048575);
    const int    r = w >> 9, c = w & 511;      // c multiple of 4
    *(h4*)(blk + b * 1048576 +
           ((r >> 4) * 8192 + (c >> 5) * 512 + (r & 15) * 32 + (c & 31))) = hh;
}

// ---------------------------------------------------------------------------
// attn_fused v5 = r9 structure re-tiled for the HARD 128-VGPR cap.
// r10 post-mortem: compiler pins VGPR_Count=128 regardless of
// launch_bounds/waves_per_eu; explicit 2-deep pipelines (+112 VGPR demand)
// spilled 146MB and regressed 242->322us. Fix: REDUCE demand to <128 and
// get latency hiding from TLP instead of ILP.
//   * 512 threads / 8 waves per block (same block work: n-tile 32, all m).
//   * S-phase: wave owns m-slice 32 -> sa[2][2] (16 regs, was 32).
//   * PV-phase: wave owns c-slice 64 -> o[4][2]  (32 regs, was 64).
//   * mask mk[2][2] (16, was 32). Total demand ~110 < 128 -> NO spill.
//   * Occupancy: 2 blocks/CU x 8 waves = 4 waves/SIMD (VGPR 128 = 4/EU cap).
//   * Simple r9-style loads (no manual pipelining -- that spilled).
// PL swizzle: write at linear-m byte off (wv<<6)+(i<<5)+(quad<<3), XOR
// ((n&7)<<4) -- same involution both sides as silicon-proven r6/r9; read
// side unchanged. MXS/LSS -> [8][32]. Semantics byte-equivalent to r9.
// ---------------------------------------------------------------------------
__global__ __launch_bounds__(512) void attn_fused(
    const _Float16* __restrict__ EBg,  // enc blocked
    const _Float16* __restrict__ DBg,  // dec blocked
    const _Float16* __restrict__ VBg,  // v blocked
    const float*    __restrict__ Mg,   // mask [8][2048][2048] fp32
    _Float16* __restrict__ Gg)         // g out [8][2048][512] linear
{
    __shared__ _Float16 PL[32 * 256];      // P tile, 16 KB, XOR-swizzled
    __shared__ float MXS[8][32];
    __shared__ float LSS[8][32];

    const int id = blockIdx.x;
    const int bz = id & 7;                 // batch -> XCD
    const int n0 = (id >> 3) * 32;

    const _Float16* E0 = EBg + (size_t)bz * ((size_t)Mm * Cc);
    const _Float16* D0 = DBg + (size_t)bz * ((size_t)Nn * Cc);
    const _Float16* V0 = VBg + (size_t)bz * ((size_t)Cc * Mm);
    const float*    M0 = Mg  + (size_t)bz * ((size_t)Nn * Mm);

    const int tid = threadIdx.x;
    const int wv = tid >> 6, ln = tid & 63;     // wv 0..7
    const int lcol = ln & 15, quad = ln >> 4;
    const int eoff = lcol * 32 + quad * 8;      // lane offset within 1KB frag
    char* PLb = (char*)PL;

    // fragment base pointers
    const _Float16* Qf = D0 + (n0 >> 4) * 8192 + eoff;        // + j*8192 + t*512
    const _Float16* Ef = E0 + (size_t)(wv * 2) * 8192 + eoff; // + ((m0>>4)+i)*8192 + t*512
    const _Float16* Vf = V0 + (size_t)(wv * 4) * 32768 + eoff;// + i*32768 + ((m0>>5)+t)*512

    f4 o[4][2];                            // c = wv*64+i*16+quad*4+r, n = j*16+lcol
    const f4 z4 = {0.f, 0.f, 0.f, 0.f};
    #pragma unroll
    for (int i = 0; i < 4; ++i)
        #pragma unroll
        for (int j = 0; j < 2; ++j) o[i][j] = z4;
    float mrun[2] = {0.f, 0.f};            // init 0 = masked zeros participate
    float lrun[2] = {0.f, 0.f};

    for (int mt = 0; mt < 8; ++mt) {
        const int m0 = mt * 256;

        // ---- mask loads (wave's m-slice 32), issued before S-phase -----
        const float* Mkb = M0 + (size_t)(n0 + lcol) * Mm + m0 + wv * 32 + quad * 4;
        f4 mk[2][2];
        #pragma unroll
        for (int j = 0; j < 2; ++j)
            #pragma unroll
            for (int i = 0; i < 2; ++i)
                mk[j][i] = *(const f4*)(Mkb + (size_t)j * 16 * Mm + i * 16);

        // ---- S-phase: sa += enc x Q (coalesced direct loads) -----------
        f4 sa[2][2];
        #pragma unroll
        for (int i = 0; i < 2; ++i)
            #pragma unroll
            for (int j = 0; j < 2; ++j) sa[i][j] = z4;

        #pragma unroll
        for (int t = 0; t < 16; ++t) {
            hfrag af[2], bf[2];
            #pragma unroll
            for (int i = 0; i < 2; ++i)
                af[i] = *(const hfrag*)(Ef + (size_t)((m0 >> 4) + i) * 8192 + t * 512);
            #pragma unroll
            for (int j = 0; j < 2; ++j)
                bf[j] = *(const hfrag*)(Qf + (size_t)j * 8192 + t * 512);
            #pragma unroll
            for (int i = 0; i < 2; ++i)
                #pragma unroll
                for (int j = 0; j < 2; ++j)
                    sa[i][j] = __builtin_amdgcn_mfma_f32_16x16x32_f16(af[i], bf[j], sa[i][j], 0, 0, 0);
        }

        // ---- A-phase: mask + wave-local max ----------------------------
        #pragma unroll
        for (int j = 0; j < 2; ++j) {
            #pragma unroll
            for (int i = 0; i < 2; ++i)
                #pragma unroll
                for (int r = 0; r < 4; ++r) sa[i][j][r] *= mk[j][i][r];
            float mx = 0.f;
            #pragma unroll
            for (int i = 0; i < 2; ++i)
                #pragma unroll
                for (int r = 0; r < 4; ++r) mx = fmaxf(mx, sa[i][j][r]);
            mx = fmaxf(mx, __shfl_xor(mx, 16, 64));
            mx = fmaxf(mx, __shfl_xor(mx, 32, 64));
            if (quad == 0) MXS[wv][j * 16 + lcol] = mx;
        }
        __syncthreads();                                   // S1

        // ---- B-phase: m_new/alpha, P -> PL, l-partials -----------------
        float al[2], mnew[2];
        #pragma unroll
        for (int j = 0; j < 2; ++j) {
            const int n = j * 16 + lcol;
            float mm = mrun[j];
            #pragma unroll
            for (int w = 0; w < 8; ++w) mm = fmaxf(mm, MXS[w][n]);
            al[j] = __expf(mrun[j] - mm);
            mrun[j] = mm; mnew[j] = mm;
        }
        #pragma unroll
        for (int j = 0; j < 2; ++j) {
            const int n = j * 16 + lcol;
            float lp = 0.f;
            #pragma unroll
            for (int i = 0; i < 2; ++i) {
                h4 pv;
                #pragma unroll
                for (int r = 0; r < 4; ++r) {
                    const float s = sa[i][j][r];
                    const float e = __expf(s - mnew[j]);
                    lp += e;
                    pv[r] = (s == 0.f) ? (_Float16)0.f : (_Float16)e;
                }
                *(h4*)(PLb + n * 512 +
                       (((wv << 6) + (i << 5) + (quad << 3)) ^ ((n & 7) << 4))) = pv;
            }
            lp += __shfl_xor(lp, 16, 64);
            lp += __shfl_xor(lp, 32, 64);
            if (quad == 0) LSS[wv][n] = lp;
        }
        __syncthreads();                                   // S2

        // ---- C-phase: l_run update + o rescale -------------------------
        #pragma unroll
        for (int j = 0; j < 2; ++j) {
            const int n = j * 16 + lcol;
            float ls = 0.f;
            #pragma unroll
            for (int w = 0; w < 8; ++w) ls += LSS[w][n];
            lrun[j] = lrun[j] * al[j] + ls;
            #pragma unroll
            for (int i = 0; i < 4; ++i)
                #pragma unroll
                for (int r = 0; r < 4; ++r) o[i][j][r] *= al[j];
        }

        // ---- PV-phase: o += v x P (coalesced V, P from PL) -------------
        #pragma unroll
        for (int t = 0; t < 8; ++t) {
            hfrag va[4], pb[2];
            #pragma unroll
            for (int i = 0; i < 4; ++i)
                va[i] = *(const hfrag*)(Vf + (size_t)i * 32768 + (size_t)((m0 >> 5) + t) * 512);
            #pragma unroll
            for (int j = 0; j < 2; ++j) {
                const int n = j * 16 + lcol;
                pb[j] = *(const hfrag*)(PLb + n * 512 +
                        (((t << 6) + (quad << 4)) ^ ((n & 7) << 4)));
            }
            #pragma unroll
            for (int i = 0; i < 4; ++i)
                #pragma unroll
                for (int j = 0; j < 2; ++j)
                    o[i][j] = __builtin_amdgcn_mfma_f32_16x16x32_f16(va[i], pb[j], o[i][j], 0, 0, 0);
        }
        __syncthreads();                                   // S3: PL reusable
    }

    // ---- finalize: g = dec * (1 + tanh(o/l)), dec read from DB blocked --
    _Float16* Gb = Gg + (size_t)bz * ((size_t)Nn * Cc);
    #pragma unroll
    for (int j = 0; j < 2; ++j) {
        const int n = n0 + j * 16 + lcol;
        const float inv = 1.f / lrun[j];
        const _Float16* Dn = D0 + (size_t)(n >> 4) * 8192 + (n & 15) * 32;
        #pragma unroll
        for (int i = 0; i < 4; ++i) {
            const int c0 = wv * 64 + i * 16 + quad * 4;
            const h4 dv = *(const h4*)(Dn + (c0 >> 5) * 512 + (c0 & 31));
            h4 gv;
            #pragma unroll
            for (int r = 0; r < 4; ++r) {
                const float a = o[i][j][r] * inv;
                const float th = 1.f - 2.f / (__expf(2.f * a) + 1.f);
                gv[r] = (_Float16)((float)dv[r] * (1.f + th));
            }
            *(h4*)(Gb + (size_t)n * Cc + c0) = gv;
        }
    }
}

// ---------------------------------------------------------------------------
// MFMA GEMM (f16 in, fp32 acc), 128xBN tile, BK=32, ring-of-3 LDS buffers,
// counted vmcnt + raw s_barrier (r3 structure, verified). EPI 1/3/4.
// EPI1 writes v into BLOCKED layout VB[b][c/16][m/32][16][32].
// ---------------------------------------------------------------------------
template<int EPI, int BN, int SWZ>
__global__ __launch_bounds__(256) void gemm_mfma(
    const _Float16* __restrict__ Ah, long sA, int lda,
    const _Float16* __restrict__ Bh, long sB, int ldb,
    const float* __restrict__ aux, long sAux, int ldaux,     // f32 bias
    void* __restrict__ Cout, long sC, int ldc, int K, int GX)
{
    constexpr int NI  = (BN == 128) ? 4 : 2;
    constexpr int ASL = 512;
    constexpr int BSL = BN * 4;
    constexpr int NQ  = (ASL + BSL) / 256;

    __shared__ _Float16 As[3][128 * 32];
    __shared__ _Float16 Bs[3][BN * 32];

    int bx, by, bz;
    if (SWZ == 1) {
        const int id = blockIdx.x;
        bz = id & 7; bx = (id >> 3) % GX; by = (id >> 3) / GX;
    } else if (SWZ == 2) {
        const int id = blockIdx.x;
        bz = 0; bx = (id >> 3) % GX; by = (id & 7) + 8 * ((id >> 3) / GX);
    } else {
        bx = blockIdx.x; by = blockIdx.y; bz = 0;
    }

    const _Float16* A0 = Ah + (size_t)bz * sA;
    const _Float16* B0 = Bh + (size_t)bz * sB;

    const int tid  = threadIdx.x;
    const int wv   = tid >> 6;
    const int ln   = tid & 63;
    const int wx   = (BN == 128) ? (wv & 1) : 0;
    const int wy   = (BN == 128) ? (wv >> 1) : wv;
    const int lcol = ln & 15, quad = ln >> 4;
    const int row0w = wy * (NI * 16);
    const int col0w = wx * 64;

    const int rowBase = by * 128;
    const int colBase = bx * BN;
    const int soff = (quad ^ ((lcol >> 1) & 3)) * 8;

    f4 acc[NI][4];
    const f4 z4 = {0.f, 0.f, 0.f, 0.f};
    #pragma unroll
    for (int i = 0; i < NI; ++i)
        #pragma unroll
        for (int j = 0; j < 4; ++j) acc[i][j] = z4;

    auto STAGE = [&](int k0, int p) {
        #pragma unroll
        for (int q = 0; q < NQ; ++q) {
            const int c = q * 256 + wv * 64 + ln;
            if (c < ASL) {
                const int r = c >> 2;
                const int g = (c & 3) ^ ((c >> 3) & 3);
                gld16(A0 + (size_t)(rowBase + r) * lda + k0 + g * 8, &As[p][c * 8]);
            } else {
                const int cb = c - ASL;
                const int r  = cb >> 2;
                const int g  = (cb & 3) ^ ((cb >> 3) & 3);
                gld16(B0 + (size_t)(colBase + r) * ldb + k0 + g * 8, &Bs[p][cb * 8]);
            }
        }
    };

    const int NT = K >> 5;
    STAGE(0, 0);
    STAGE(32, 1);
    wait_vmcnt<NQ>();
    __builtin_amdgcn_s_barrier();

    int p = 0, pn2 = 2;
    for (int t = 0; t < NT; ++t) {
        if (t + 2 < NT) STAGE((t + 2) * 32, pn2);

        hfrag af[NI], bf_[4];
        #pragma unroll
        for (int i = 0; i < NI; ++i)
            af[i]  = *(const hfrag*)&As[p][(row0w + i * 16 + lcol) * 32 + soff];
        #pragma unroll
        for (int j = 0; j < 4; ++j)
            bf_[j] = *(const hfrag*)&Bs[p][(col0w + j * 16 + lcol) * 32 + soff];

        #pragma unroll
        for (int i = 0; i < NI; ++i)
            #pragma unroll
            for (int j = 0; j < 4; ++j)
                acc[i][j] = __builtin_amdgcn_mfma_f32_16x16x32_f16(af[i], bf_[j], acc[i][j], 0, 0, 0);

        if (t + 1 < NT) {
            if (t + 2 < NT) wait_vmcnt<NQ>();
            else            wait_vmcnt<0>();
            __builtin_amdgcn_s_barrier();
        }
        p   = (p   == 2) ? 0 : p + 1;
        pn2 = (pn2 == 2) ? 0 : pn2 + 1;
    }

    const int crow0 = rowBase + row0w + quad * 4;
    const int ccol0 = colBase + col0w + lcol;

    if (EPI == 1) {            // v blocked: VB[b][c/16][m/32][16][32]
        _Float16* C = (_Float16*)Cout;
        #pragma unroll
        for (int j = 0; j < 4; ++j) {
            const int col = ccol0 + j * 16;          // c index
            const float bi = aux[col];
            #pragma unroll
            for (int i = 0; i < NI; ++i) {
                const int rowb = crow0 + i * 16;     // flattened b*M + m
                const int bb = rowb >> 11, ml = rowb & 2047;
                h4 st;
                #pragma unroll
                for (int r = 0; r < 4; ++r) st[r] = (_Float16)(acc[i][j][r] + bi);
                *(h4*)(C + (size_t)bb * 1048576 +
                       ((col >> 4) * 32768 + (ml >> 5) * 512 +
                        (col & 15) * 32 + (ml & 31))) = st;
            }
        }
    } else if (EPI == 3) {     // fc1: h[n][c2] = relu(acc + b1[c2]), h4
        _Float16* C = (_Float16*)Cout;
        #pragma unroll
        for (int i = 0; i < NI; ++i) {
            const int c0 = crow0 + i * 16;
            const f4 bi = *(const f4*)(aux + c0);
            #pragma unroll
            for (int j = 0; j < 4; ++j) {
                const int n = ccol0 + j * 16;
                h4 hv;
                #pragma unroll
                for (int r = 0; r < 4; ++r)
                    hv[r] = (_Float16)fmaxf(acc[i][j][r] + bi[r], 0.f);
                *(h4*)(C + (size_t)n * ldc + c0) = hv;
            }
        }
    } else {                   // fc2: out[n][c3] = acc + b2[c3], f4 stores
        float* C = (float*)Cout;
        #pragma unroll
        for (int i = 0; i < NI; ++i) {
            const int c0 = crow0 + i * 16;
            const f4 bi = *(const f4*)(aux + c0);
            #pragma unroll
            for (int j = 0; j < 4; ++j) {
                const int n = ccol0 + j * 16;
                f4 ov;
                #pragma unroll
                for (int r = 0; r < 4; ++r) ov[r] = acc[i][j][r] + bi[r];
                *(f4*)(C + (size_t)n * ldc + c0) = ov;
            }
        }
    }
}

// W [512,512] fp32 -> Wt [512,512] f16 transposed (Wt[n][k] = W[k][n]).
__global__ __launch_bounds__(256) void wconv(const float* s0, const float* s1, const float* s2,
                                             _Float16* d0, _Float16* d1, _Float16* d2)
{
    const float* Sm = blockIdx.z == 0 ? s0 : blockIdx.z == 1 ? s1 : s2;
    _Float16* D = blockIdx.z == 0 ? d0 : blockIdx.z == 1 ? d1 : d2;
    __shared__ float t[32][33];
    const int x = threadIdx.x & 31, y = threadIdx.x >> 5;
    const int gx = blockIdx.x * 32, gy = blockIdx.y * 32;
    #pragma unroll
    for (int yy = y; yy < 32; yy += 8)
        t[yy][x] = Sm[(size_t)(gy + yy) * 512 + gx + x];
    __syncthreads();
    #pragma unroll
    for (int yy = y; yy < 32; yy += 8)
        D[(size_t)(gx + yy) * 512 + gy + x] = (_Float16)t[x][yy];
}

// ---------------------------------------------------------------------------
// ws layout (all within proven 142MB envelope):
//   EB   [0x0000000, 0x1000000)  enc blocked f16
//   DB   [0x1000000, 0x2000000)  dec blocked f16
//   VB   [0x2000000, 0x3000000)  v blocked f16
//   Wvt/W1t/W2t [0x5600000, +3*512KB)
//   g    [0x6800000, 0x7800000)  f16 [bn][c]
//   h    [0x7800000, 0x8800000)  f16 [bn][c2]
//   enc_h linear in d_out (dead before fc2 writes).
// ---------------------------------------------------------------------------
extern "C" void kernel_launch(void* const* d_in, const int* in_sizes, int n_in,
                              void* d_out, int out_size, void* d_ws, size_t ws_size,
                              hipStream_t stream)
{
    const float* dec   = (const float*)d_in[0];
    const float* enc   = (const float*)d_in[1];
    const float* trans = (const float*)d_in[2];
    const float* Wv = (const float*)d_in[3];
    const float* bv = (const float*)d_in[4];
    const float* W1 = (const float*)d_in[5];
    const float* b1 = (const float*)d_in[6];
    const float* W2 = (const float*)d_in[7];
    const float* b2 = (const float*)d_in[8];

    char* ws = (char*)d_ws;
    _Float16* EBw   = (_Float16*)ws;
    _Float16* DBw   = (_Float16*)(ws + 0x1000000);
    _Float16* VBw   = (_Float16*)(ws + 0x2000000);
    _Float16* Wvt   = (_Float16*)(ws + 0x5600000);
    _Float16* W1t   = Wvt + 262144;
    _Float16* W2t   = Wvt + 524288;
    _Float16* g     = (_Float16*)(ws + 0x6800000);
    _Float16* h     = (_Float16*)(ws + 0x7800000);
    _Float16* enc_h = (_Float16*)d_out;

    sconv2<<<dim3(8192), 256, 0, stream>>>(dec, nullptr, DBw);
    sconv2<<<dim3(8192), 256, 0, stream>>>(enc, enc_h, EBw);
    wconv<<<dim3(16, 16, 3), 256, 0, stream>>>(Wv, W1, W2, Wvt, W1t, W2t);

    // v = (enc @ Wv + bv), written fragment-blocked  [SWZ2, GX=8]
    gemm_mfma<1, 64, 2><<<dim3(1024), 256, 0, stream>>>(
        enc_h, 0, 512, Wvt, 0, 512, bv, 0, 0,
        VBw, 0, 0, 512, 8);

    // fused: score + masked-softmax + PV + gate -> g  (8 waves, 512 thr)
    attn_fused<<<dim3(512), 512, 0, stream>>>(EBw, DBw, VBw, trans, g);

    // h[n][c2] = relu(g @ W1 + b1):  A=W1^T (rows=c2), B=g (cols=n)
    gemm_mfma<3, 64, 0><<<dim3(256, 4), 256, 0, stream>>>(
        W1t, 0, 512, g, 0, 512, b1, 0, 0,
        h, 0, 512, 512, 0);

    // out[n][c3] = h @ W2 + b2:  A=W2^T (rows=c3), B=h (cols=n), fp32
    gemm_mfma<4, 64, 0><<<dim3(256, 4), 256, 0, stream>>>(
        W2t, 0, 512, h, 0, 512, b2, 0, 0,
        d_out, 0, 512, 512, 0);
}